// Round 1
// baseline (181.797 us; speedup 1.0000x reference)
//
#include <hip/hip_runtime.h>
#include <hip/hip_bf16.h>

#define T_SEQ 512
#define NH 8
#define DEPTH 64
#define UNITS_ 512
#define SCALE2 2.8853900817779268f   // 2*log2(e)
#define LOG2E 1.4426950408889634f

typedef __attribute__((ext_vector_type(8))) short short8;
typedef __attribute__((ext_vector_type(4))) float floatx4;

// ================= fused QK projection + per-head transform =================
// z=0: C = query@Wq+bq (64x64 tile = one head's depth), then
//      eq[b,h,t,e] = exp2(SCALE2 * (C @ Wq_h[h])[t,e])
// z=1: C = key@Wk+bk, then
//      ekT[b,h,e,s] = exp2(SCALE2 * ((C @ Wk_h[h])[s,e] + b_h[h,e]))  (transposed)
//      KhT[b,h,d,s] = bf16(C[s,d])                                    (transposed)
// Main loop: 64x64 tile, 4x4/thread, register-prefetch double buffering.
__global__ __launch_bounds__(256) void qk_head_fused(
    const float* __restrict__ query, const float* __restrict__ key,
    const float* __restrict__ Wq, const float* __restrict__ bq,
    const float* __restrict__ Wk, const float* __restrict__ bk,
    const float* __restrict__ Wq_h, const float* __restrict__ Wk_h,
    const float* __restrict__ bh,
    float* __restrict__ eq, float* __restrict__ ekT,
    __hip_bfloat16* __restrict__ KhT)
{
    __shared__ float S1[64][68];   // stage1: rows 0..31 = As [k][m]; stage2: C^T [d][s] (+bias)
    __shared__ float S2[64][68];   // stage1: rows 0..31 = Bs [k][n]; stage2: Wh [d][e], then e-transpose scratch

    const int tid = threadIdx.x;
    const int which = blockIdx.z;            // 0 = Q path, 1 = K path
    const int h  = blockIdx.x;               // head (n-tile == head depth)
    const int m0 = blockIdx.y * 64;          // row in [0,1024): b*512 + t
    const int n0 = h * 64;
    const int b  = m0 >> 9;
    const int t0 = m0 & 511;
    const int bh_i = b * NH + h;

    const float* In   = which ? key : query;
    const float* W    = which ? Wk  : Wq;
    const float* bias = which ? bk  : bq;
    const float* Wp   = (which ? Wk_h : Wq_h) + h * 4096;

    float (*As)[68] = S1;
    float (*Bs)[68] = S2;

    const int arow = tid >> 2;          // m 0..63
    const int acol = (tid & 3) * 8;     // k base 0,8,16,24
    const int bkk = tid >> 3;           // k 0..31
    const int bn = (tid & 7) * 8;       // n base

    const int ti = tid >> 4;            // 0..15
    const int tj = tid & 15;            // 0..15

    // early prefetch of the per-head weight tile (held in regs through main loop)
    const int wrow = tid >> 2;          // d 0..63
    const int wcol = (tid & 3) * 16;    // e base
    float4 wh0 = *(const float4*)&Wp[wrow * 64 + wcol + 0];
    float4 wh1 = *(const float4*)&Wp[wrow * 64 + wcol + 4];
    float4 wh2 = *(const float4*)&Wp[wrow * 64 + wcol + 8];
    float4 wh3 = *(const float4*)&Wp[wrow * 64 + wcol + 12];

    float4 acc[4];
    acc[0] = acc[1] = acc[2] = acc[3] = make_float4(0.f, 0.f, 0.f, 0.f);

    // prefetch k-tile 0
    float4 av0 = *(const float4*)&In[(m0 + arow) * 512 + acol];
    float4 av1 = *(const float4*)&In[(m0 + arow) * 512 + acol + 4];
    float4 bv0 = *(const float4*)&W[bkk * 512 + n0 + bn];
    float4 bv1 = *(const float4*)&W[bkk * 512 + n0 + bn + 4];

    for (int k0 = 0; k0 < 512; k0 += 32) {
        __syncthreads();
        As[acol + 0][arow] = av0.x;
        As[acol + 1][arow] = av0.y;
        As[acol + 2][arow] = av0.z;
        As[acol + 3][arow] = av0.w;
        As[acol + 4][arow] = av1.x;
        As[acol + 5][arow] = av1.y;
        As[acol + 6][arow] = av1.z;
        As[acol + 7][arow] = av1.w;
        *(float4*)&Bs[bkk][bn] = bv0;
        *(float4*)&Bs[bkk][bn + 4] = bv1;
        __syncthreads();
        if (k0 + 32 < 512) {   // prefetch next k-tile; latency hides under the fma block
            av0 = *(const float4*)&In[(m0 + arow) * 512 + k0 + 32 + acol];
            av1 = *(const float4*)&In[(m0 + arow) * 512 + k0 + 32 + acol + 4];
            bv0 = *(const float4*)&W[(k0 + 32 + bkk) * 512 + n0 + bn];
            bv1 = *(const float4*)&W[(k0 + 32 + bkk) * 512 + n0 + bn + 4];
        }
        #pragma unroll
        for (int kk = 0; kk < 32; ++kk) {
            float4 a4 = *(const float4*)&As[kk][4 * ti];
            float4 b4 = *(const float4*)&Bs[kk][4 * tj];
            acc[0].x = fmaf(a4.x, b4.x, acc[0].x);
            acc[0].y = fmaf(a4.x, b4.y, acc[0].y);
            acc[0].z = fmaf(a4.x, b4.z, acc[0].z);
            acc[0].w = fmaf(a4.x, b4.w, acc[0].w);
            acc[1].x = fmaf(a4.y, b4.x, acc[1].x);
            acc[1].y = fmaf(a4.y, b4.y, acc[1].y);
            acc[1].z = fmaf(a4.y, b4.z, acc[1].z);
            acc[1].w = fmaf(a4.y, b4.w, acc[1].w);
            acc[2].x = fmaf(a4.z, b4.x, acc[2].x);
            acc[2].y = fmaf(a4.z, b4.y, acc[2].y);
            acc[2].z = fmaf(a4.z, b4.z, acc[2].z);
            acc[2].w = fmaf(a4.z, b4.w, acc[2].w);
            acc[3].x = fmaf(a4.w, b4.x, acc[3].x);
            acc[3].y = fmaf(a4.w, b4.y, acc[3].y);
            acc[3].z = fmaf(a4.w, b4.z, acc[3].z);
            acc[3].w = fmaf(a4.w, b4.w, acc[3].w);
        }
    }

    // ---- stage 2: per-head 64x64 transform (transplanted head_xform) ----
    float4 bb = *(const float4*)&bias[n0 + 4 * tj];
    __syncthreads();   // all waves done reading As/Bs
    // C^T (+bias) into S1: S1[n_local][m_local]; per thread 4 float4 rows
    *(float4*)&S1[4 * tj + 0][4 * ti] =
        make_float4(acc[0].x + bb.x, acc[1].x + bb.x, acc[2].x + bb.x, acc[3].x + bb.x);
    *(float4*)&S1[4 * tj + 1][4 * ti] =
        make_float4(acc[0].y + bb.y, acc[1].y + bb.y, acc[2].y + bb.y, acc[3].y + bb.y);
    *(float4*)&S1[4 * tj + 2][4 * ti] =
        make_float4(acc[0].z + bb.z, acc[1].z + bb.z, acc[2].z + bb.z, acc[3].z + bb.z);
    *(float4*)&S1[4 * tj + 3][4 * ti] =
        make_float4(acc[0].w + bb.w, acc[1].w + bb.w, acc[2].w + bb.w, acc[3].w + bb.w);
    // Wh into S2 [d][e] from the early-prefetched registers
    *(float4*)&S2[wrow][wcol + 0]  = wh0;
    *(float4*)&S2[wrow][wcol + 4]  = wh1;
    *(float4*)&S2[wrow][wcol + 8]  = wh2;
    *(float4*)&S2[wrow][wcol + 12] = wh3;
    __syncthreads();

    float4 qa[4];
    qa[0] = qa[1] = qa[2] = qa[3] = make_float4(0.f, 0.f, 0.f, 0.f);
    #pragma unroll 8
    for (int d = 0; d < 64; ++d) {
        float4 a4 = *(const float4*)&S1[d][4 * ti];
        float4 b4 = *(const float4*)&S2[d][4 * tj];
        qa[0].x = fmaf(a4.x, b4.x, qa[0].x);
        qa[0].y = fmaf(a4.x, b4.y, qa[0].y);
        qa[0].z = fmaf(a4.x, b4.z, qa[0].z);
        qa[0].w = fmaf(a4.x, b4.w, qa[0].w);
        qa[1].x = fmaf(a4.y, b4.x, qa[1].x);
        qa[1].y = fmaf(a4.y, b4.y, qa[1].y);
        qa[1].z = fmaf(a4.y, b4.z, qa[1].z);
        qa[1].w = fmaf(a4.y, b4.w, qa[1].w);
        qa[2].x = fmaf(a4.z, b4.x, qa[2].x);
        qa[2].y = fmaf(a4.z, b4.y, qa[2].y);
        qa[2].z = fmaf(a4.z, b4.z, qa[2].z);
        qa[2].w = fmaf(a4.z, b4.w, qa[2].w);
        qa[3].x = fmaf(a4.w, b4.x, qa[3].x);
        qa[3].y = fmaf(a4.w, b4.y, qa[3].y);
        qa[3].z = fmaf(a4.w, b4.z, qa[3].z);
        qa[3].w = fmaf(a4.w, b4.w, qa[3].w);
    }

    if (which == 0) {
        float* outp = eq + ((size_t)bh_i * 512 + t0) * 64;
        #pragma unroll
        for (int r = 0; r < 4; ++r) {
            float4 o;
            o.x = __builtin_amdgcn_exp2f(SCALE2 * qa[r].x);
            o.y = __builtin_amdgcn_exp2f(SCALE2 * qa[r].y);
            o.z = __builtin_amdgcn_exp2f(SCALE2 * qa[r].z);
            o.w = __builtin_amdgcn_exp2f(SCALE2 * qa[r].w);
            *(float4*)&outp[(4 * ti + r) * 64 + 4 * tj] = o;
        }
        return;
    }

    // which == 1: ekT (transposed, exp2'd, +b_h) and KhT (bf16 of C^T)
    float4 bhv = *(const float4*)&bh[h * 64 + 4 * tj];
    __syncthreads();   // all waves done reading S2 as Wh
    #pragma unroll
    for (int r = 0; r < 4; ++r) {
        // e = 4*tj + c (row), s_local = 4*ti + r (col)
        S2[4 * tj + 0][4 * ti + r] = __builtin_amdgcn_exp2f(SCALE2 * (qa[r].x + bhv.x));
        S2[4 * tj + 1][4 * ti + r] = __builtin_amdgcn_exp2f(SCALE2 * (qa[r].y + bhv.y));
        S2[4 * tj + 2][4 * ti + r] = __builtin_amdgcn_exp2f(SCALE2 * (qa[r].z + bhv.z));
        S2[4 * tj + 3][4 * ti + r] = __builtin_amdgcn_exp2f(SCALE2 * (qa[r].w + bhv.w));
    }
    __syncthreads();

    const int dd = tid >> 2;
    const int sc = (tid & 3) * 16;
    float* ekp = ekT + ((size_t)bh_i * 64 + dd) * 512 + t0 + sc;
    #pragma unroll
    for (int c = 0; c < 4; ++c)
        *(float4*)&ekp[4 * c] = *(float4*)&S2[dd][sc + 4 * c];

    // KhT bf16 from S1 (= projected-K^T, untouched by the transpose scratch)
    __hip_bfloat16* kp = KhT + ((size_t)bh_i * 64 + dd) * 512 + t0 + sc;
    union { short8 v; short s[8]; } pk0, pk1;
    #pragma unroll
    for (int i = 0; i < 8; ++i) {
        __hip_bfloat16 b0 = __hip_bfloat16(S1[dd][sc + i]);
        __hip_bfloat16 b1 = __hip_bfloat16(S1[dd][sc + 8 + i]);
        pk0.s[i] = *(short*)&b0;
        pk1.s[i] = *(short*)&b1;
    }
    *(short8*)kp = pk0.v;
    *(short8*)(kp + 8) = pk1.v;
}

// ============ additive-attention core (register score + MFMA P@K) ============
// score'[t,s] = sum_e (-2 va[e]) * rcp(1 + eq[t][e]*ek[e][s])   (softmax-invariant)
// p = softmax (no max-subtract: |score'| <= 2*sum|va| ~ 5, exp safe in fp32)
// out[t,d] = sum_s p[t,s]*K[s,d] via bf16 MFMA 16x16x32
__global__ __launch_bounds__(512, 4) void attn_v2(
    const float* __restrict__ eq, const float* __restrict__ ekT,
    const __hip_bfloat16* __restrict__ KhT, const float* __restrict__ va_h,
    float* __restrict__ merged)
{
    __shared__ __hip_bfloat16 pA[16][520];   // p in MFMA-A layout source, bf16
    __shared__ float wsum[16][8];

    const int tid = threadIdx.x;
    const int w = tid >> 6;
    const int l = tid & 63;
    const int t0 = blockIdx.x * 16;
    const int h = blockIdx.y;
    const int b = blockIdx.z;
    const int bh_i = b * NH + h;

    const float* eq_p = eq + ((size_t)bh_i * 512 + t0) * 64;
    const float* ekT_p = ekT + (size_t)bh_i * 64 * 512 + tid;   // this thread's s
    const float* va_p = va_h + h * 64;

    float acc[16];
    #pragma unroll
    for (int t = 0; t < 16; ++t) acc[t] = 0.f;

    #pragma unroll
    for (int e0 = 0; e0 < 64; e0 += 16) {
        float ekv[16];
        #pragma unroll
        for (int j = 0; j < 16; ++j) ekv[j] = ekT_p[(e0 + j) * 512];
        float nv[16];
        #pragma unroll
        for (int j = 0; j < 16; ++j) nv[j] = -2.0f * va_p[e0 + j];
        #pragma unroll
        for (int t = 0; t < 16; ++t) {
            float a = acc[t];
            #pragma unroll
            for (int q = 0; q < 4; ++q) {
                float4 e4 = *(const float4*)&eq_p[t * 64 + e0 + q * 4];  // uniform -> s_load
                a = fmaf(nv[q * 4 + 0], __builtin_amdgcn_rcpf(fmaf(e4.x, ekv[q * 4 + 0], 1.0f)), a);
                a = fmaf(nv[q * 4 + 1], __builtin_amdgcn_rcpf(fmaf(e4.y, ekv[q * 4 + 1], 1.0f)), a);
                a = fmaf(nv[q * 4 + 2], __builtin_amdgcn_rcpf(fmaf(e4.z, ekv[q * 4 + 2], 1.0f)), a);
                a = fmaf(nv[q * 4 + 3], __builtin_amdgcn_rcpf(fmaf(e4.w, ekv[q * 4 + 3], 1.0f)), a);
            }
            acc[t] = a;
        }
    }

    // exp (no max-subtract; bounded) + per-t sum across 512 threads
    float ev[16];
    #pragma unroll
    for (int t = 0; t < 16; ++t) {
        float s = __builtin_amdgcn_exp2f(acc[t] * LOG2E);
        ev[t] = s;
        #pragma unroll
        for (int off = 32; off > 0; off >>= 1) s += __shfl_xor(s, off, 64);
        if (l == 0) wsum[t][w] = s;
    }
    __syncthreads();
    #pragma unroll
    for (int t = 0; t < 16; ++t) {
        float4 s0 = *(float4*)&wsum[t][0];
        float4 s1 = *(float4*)&wsum[t][4];
        float inv = 1.0f / (((s0.x + s0.y) + (s0.z + s0.w)) + ((s1.x + s1.y) + (s1.z + s1.w)));
        pA[t][tid] = __hip_bfloat16(ev[t] * inv);   // normalized p, bf16
    }
    __syncthreads();

    // P (16x512) @ K (512x64): 4 waves, wave w owns d-range [16w,16w+16)
    if (w < 4) {
        const __hip_bfloat16* kp = KhT + (size_t)bh_i * 64 * 512
                                   + ((size_t)(w * 16 + (l & 15))) * 512 + (l >> 4) * 8;
        const __hip_bfloat16* ap = &pA[l & 15][(l >> 4) * 8];
        floatx4 oacc = {0.f, 0.f, 0.f, 0.f};
        #pragma unroll
        for (int kt = 0; kt < 16; ++kt) {
            short8 af = *(const short8*)(ap + kt * 32);
            short8 bf = *(const short8*)(kp + kt * 32);
            oacc = __builtin_amdgcn_mfma_f32_16x16x32_bf16(af, bf, oacc, 0, 0, 0);
        }
        const int row = (l >> 4) * 4;        // t_local base
        const int col = w * 16 + (l & 15);   // d
        float* mp = merged + ((size_t)(b * 512 + t0 + row)) * 512 + h * 64 + col;
        #pragma unroll
        for (int r = 0; r < 4; ++r) mp[r * 512] = oacc[r];
    }
}

// ================= output projection: C = A@Wo + bo =================
// 32x64 tiles -> 256 blocks (full machine), 2x4/thread, register prefetch.
__global__ __launch_bounds__(256) void gemm_out(
    const float* __restrict__ A, const float* __restrict__ W,
    const float* __restrict__ bias, float* __restrict__ C)
{
    __shared__ float As[32][36];   // [k][m]
    __shared__ float Bs[32][68];   // [k][n]

    const int tid = threadIdx.x;
    const int n0 = blockIdx.x * 64;
    const int m0 = blockIdx.y * 32;

    const int arow = tid >> 3;          // m 0..31
    const int acol = (tid & 7) * 4;     // k base 0..28
    const int bkk = tid >> 3;           // k 0..31
    const int bn = (tid & 7) * 8;       // n base

    const int ti = tid >> 4;            // m = 2*ti
    const int tj = tid & 15;            // n = 4*tj

    float4 acc0 = make_float4(0.f, 0.f, 0.f, 0.f);
    float4 acc1 = make_float4(0.f, 0.f, 0.f, 0.f);

    float4 av  = *(const float4*)&A[(m0 + arow) * 512 + acol];
    float4 bv0 = *(const float4*)&W[bkk * 512 + n0 + bn];
    float4 bv1 = *(const float4*)&W[bkk * 512 + n0 + bn + 4];

    for (int k0 = 0; k0 < 512; k0 += 32) {
        __syncthreads();
        As[acol + 0][arow] = av.x;
        As[acol + 1][arow] = av.y;
        As[acol + 2][arow] = av.z;
        As[acol + 3][arow] = av.w;
        *(float4*)&Bs[bkk][bn] = bv0;
        *(float4*)&Bs[bkk][bn + 4] = bv1;
        __syncthreads();
        if (k0 + 32 < 512) {
            av  = *(const float4*)&A[(m0 + arow) * 512 + k0 + 32 + acol];
            bv0 = *(const float4*)&W[(k0 + 32 + bkk) * 512 + n0 + bn];
            bv1 = *(const float4*)&W[(k0 + 32 + bkk) * 512 + n0 + bn + 4];
        }
        #pragma unroll
        for (int kk = 0; kk < 32; ++kk) {
            float2 a2 = *(const float2*)&As[kk][2 * ti];
            float4 b4 = *(const float4*)&Bs[kk][4 * tj];
            acc0.x = fmaf(a2.x, b4.x, acc0.x);
            acc0.y = fmaf(a2.x, b4.y, acc0.y);
            acc0.z = fmaf(a2.x, b4.z, acc0.z);
            acc0.w = fmaf(a2.x, b4.w, acc0.w);
            acc1.x = fmaf(a2.y, b4.x, acc1.x);
            acc1.y = fmaf(a2.y, b4.y, acc1.y);
            acc1.z = fmaf(a2.y, b4.z, acc1.z);
            acc1.w = fmaf(a2.y, b4.w, acc1.w);
        }
    }
    float4 bb = *(const float4*)&bias[n0 + 4 * tj];
    float4 o0, o1;
    o0.x = acc0.x + bb.x; o0.y = acc0.y + bb.y; o0.z = acc0.z + bb.z; o0.w = acc0.w + bb.w;
    o1.x = acc1.x + bb.x; o1.y = acc1.y + bb.y; o1.z = acc1.z + bb.z; o1.w = acc1.w + bb.w;
    *(float4*)&C[(m0 + 2 * ti) * 512 + n0 + 4 * tj] = o0;
    *(float4*)&C[(m0 + 2 * ti + 1) * 512 + n0 + 4 * tj] = o1;
}

extern "C" void kernel_launch(void* const* d_in, const int* in_sizes, int n_in,
                              void* d_out, int out_size, void* d_ws, size_t ws_size,
                              hipStream_t stream) {
    (void)in_sizes; (void)n_in; (void)out_size; (void)ws_size;
    const float* query = (const float*)d_in[0];
    const float* key   = (const float*)d_in[1];
    // d_in[2] (value), d_in[7] (Wv), d_in[8] (bv): dead in the reference
    const float* Wq   = (const float*)d_in[3];
    const float* bq   = (const float*)d_in[4];
    const float* Wk   = (const float*)d_in[5];
    const float* bk   = (const float*)d_in[6];
    const float* Wq_h = (const float*)d_in[9];
    const float* Wk_h = (const float*)d_in[10];
    const float* va_h = (const float*)d_in[11];
    const float* b_h  = (const float*)d_in[12];
    const float* Wo   = (const float*)d_in[13];
    const float* bo   = (const float*)d_in[14];

    float* out = (float*)d_out;
    float* ws = (float*)d_ws;
    const int SZ = 1024 * 512;        // 524288 floats
    float* eqb     = ws;
    float* ekTb    = eqb + SZ;
    float* mergedb = ekTb + SZ;
    __hip_bfloat16* KhTb = (__hip_bfloat16*)(mergedb + SZ);   // 524288 bf16

    // fused: {Q,K} = In@W+b, then per-head transform -> eq / ekT / KhT
    qk_head_fused<<<dim3(8, 16, 2), 256, 0, stream>>>(query, key, Wq, bq, Wk, bk,
                                                      Wq_h, Wk_h, b_h,
                                                      eqb, ekTb, KhTb);
    // scores -> softmax -> P@K (MFMA)
    attn_v2<<<dim3(32, 8, 2), 512, 0, stream>>>(eqb, ekTb, KhTb, va_h, mergedb);
    // out = merged@Wo + bo  (256 blocks: full machine)
    gemm_out<<<dim3(8, 32, 1), 256, 0, stream>>>(mergedb, Wo, bo, out);
}